// Round 5
// baseline (158.755 us; speedup 1.0000x reference)
//
#include <hip/hip_runtime.h>

// Problem constants (fixed by reference)
#define B_ 16
#define C_ 64
#define T_ 2048
#define O_ 64
#define KNN 3
#define HSPLIT 4
#define JCH (T_ / HSPLIT)     // 512 j per (b,h) chunk
#define NJS (JCH / 32)        // 16 staged 32-row j-subtiles per chunk

typedef short short8   __attribute__((ext_vector_type(8)));   // 8 bf16
typedef float f32x4    __attribute__((ext_vector_type(4)));
typedef unsigned short ushortx4 __attribute__((ext_vector_type(4)));

// Workspace layout (float slots). Total ~18.0 MB (< 21.2 MB proven footprint).
#define XT_OFF 0                              // fp32 xT[b][t][c]          : B*T*64
#define XS_OFF (XT_OFF + B_ * T_ * C_)        // ushort xs[b][t][128] hi|lo
#define NSQ_OFF (XS_OFF + B_ * T_ * C_)       // fp32 nsq[b*T+t]
#define WT_OFF (NSQ_OFF + B_ * T_)            // fp32 Wt[m][o], m=k*64+c   : 192*64
#define CAND_OFF (WT_OFF + 192 * O_)          // ushort cand[B*T][16]

__device__ inline ushort bf16_rne(float f) {
    union { float f; unsigned u; } cv; cv.f = f;
    unsigned u = cv.u;
    u += 0x7FFF + ((u >> 16) & 1);
    return (ushort)(u >> 16);
}
__device__ inline float bf16_val(ushort h) {
    union { unsigned u; float f; } cv; cv.u = ((unsigned)h) << 16; return cv.f;
}

// ---------------------------------------------------------------------------
// Prep (validated R4-R6): x (B,C,T) -> xT (B,T,C) fp32, xs bf16 [hi|lo], nsq,
//       W (O,C,K) -> Wt[k*64+c][o]
// ---------------------------------------------------------------------------
__global__ __launch_bounds__(256) void prep_kernel(const float* __restrict__ x,
                                                   const float* __restrict__ W,
                                                   float* __restrict__ ws) {
    float*  xT  = ws + XT_OFF;
    ushort* xs  = (ushort*)(ws + XS_OFF);
    float*  nsq = ws + NSQ_OFF;
    float*  Wt  = ws + WT_OFF;
    int blk = blockIdx.x;
    int tid = threadIdx.x;
    if (blk < B_ * (T_ / 64)) {
        int b  = blk / (T_ / 64);
        int t0 = (blk % (T_ / 64)) * 64;
        __shared__ float tl[64 * 65];
        #pragma unroll
        for (int r = 0; r < 16; ++r) {
            int e = r * 256 + tid;
            int c = e >> 6, t = e & 63;
            tl[c * 65 + t] = x[(b * C_ + c) * T_ + t0 + t];
        }
        __syncthreads();
        #pragma unroll
        for (int r = 0; r < 16; ++r) {
            int e = r * 256 + tid;
            int t = e >> 6, c = e & 63;
            float v = tl[c * 65 + t];
            size_t rowg = (size_t)(b * T_ + t0 + t);
            xT[rowg * 64 + c] = v;
            ushort hi = bf16_rne(v);
            float  fr = v - bf16_val(hi);
            ushort lo = bf16_rne(fr);
            xs[rowg * 128 + c]      = hi;
            xs[rowg * 128 + 64 + c] = lo;
        }
        if (tid < 64) {
            float s = 0.f;
            #pragma unroll
            for (int c = 0; c < 64; ++c) { float v = tl[c * 65 + tid]; s = fmaf(v, v, s); }
            nsq[b * T_ + t0 + tid] = s;
        }
    } else {
        int e = (blk - B_ * (T_ / 64)) * 256 + tid;
        if (e < O_ * C_ * KNN) {
            int o = e / (C_ * KNN);
            int c = (e / KNN) % C_;
            int k = e % KNN;
            Wt[(k * 64 + c) * O_ + o] = W[e];
        }
    }
}

// ---------------------------------------------------------------------------
// KNN screen v4 (MFMA) + XCD pinning: batch b runs only on XCD b%8 (2
// batches/XCD) so xs/nsq stay L2-resident per XCD. Counted-vmcnt 3-deep DMA
// pipeline (T3/T4) unchanged.
// ---------------------------------------------------------------------------
__global__ __launch_bounds__(256, 4) void knn_mfma_kernel(const ushort* __restrict__ xs,
                                                          const float* __restrict__ nsq,
                                                          ushort* __restrict__ cand) {
    __shared__ __align__(16) ushort jbuf[4][32 * 128];   // 4 x 8 KB, XOR-swizzled
    __shared__ float nsqs[JCH];                          // 2 KB

    int bid = blockIdx.x;
    // XCD-pinned bijective decode: XCD = bid%8 owns batches {bid%8, bid%8+8}
    int b   = (bid & 7) + 8 * (bid >> 9);
    int h   = (bid >> 3) & 3;
    int m   = (bid >> 5) & 15;
    int i0  = m * 128;
    int tid = threadIdx.x;
    int w   = tid >> 6, l = tid & 63, lr = l & 15, lq = l >> 4;
    const ushort* xsb = xs + (size_t)b * T_ * 128;
    int jBase = h * JCH;

    if (tid < JCH / 4)
        ((float4*)nsqs)[tid] = ((const float4*)(nsq + b * T_ + jBase))[tid];

    // B-operand frags for 2 i-sets: rows i0+w*32+lr (A) and +16 (B)
    short8 bA0, bA1, bA4, bA5, bB0, bB1, bB4, bB5;
    {
        const ushort* ia = xsb + (size_t)(i0 + w * 32 + lr) * 128 + lq * 8;
        bA0 = *(const short8*)(ia + 0);  bA1 = *(const short8*)(ia + 32);
        bA4 = *(const short8*)(ia + 64); bA5 = *(const short8*)(ia + 96);
        const ushort* ib2 = ia + 16 * 128;
        bB0 = *(const short8*)(ib2 + 0);  bB1 = *(const short8*)(ib2 + 32);
        bB4 = *(const short8*)(ib2 + 64); bB5 = *(const short8*)(ib2 + 96);
    }
    float niA = nsq[b * T_ + i0 + w * 32 + lr] + 4.0f;
    float niB = nsq[b * T_ + i0 + w * 32 + 16 + lr] + 4.0f;

    const float INF = __builtin_inff();
    float kA0 = INF, kA1 = INF, kA2 = INF, kA3 = INF;
    float kB0 = INF, kB1 = INF, kB2 = INF, kB3 = INF;

    int cSw = lr ^ (w * 4 + lq);                 // swizzled source chunk
    #define ISSUE_DMA(jsv, bufv) {                                               \
        _Pragma("unroll")                                                        \
        for (int p = 0; p < 2; ++p) {                                            \
            int rloc = p * 16 + w * 4 + lq;                                      \
            const ushort* gp = xsb + (size_t)(jBase + (jsv) * 32 + rloc) * 128 + cSw * 8; \
            __builtin_amdgcn_global_load_lds(                                    \
                (const __attribute__((address_space(1))) void*)gp,               \
                (__attribute__((address_space(3))) void*)(jbuf[bufv] + (p * 16 + w * 4) * 128), \
                16, 0, 0);                                                       \
        } }

    // Drain the nsqs ds_write so it is visible to all waves after barrier 0.
    asm volatile("s_waitcnt lgkmcnt(0)" ::: "memory");

    // Prologue: 3 subtiles in flight.
    ISSUE_DMA(0, 0);
    ISSUE_DMA(1, 1);
    ISSUE_DMA(2, 2);

    #pragma unroll 1
    for (int js = 0; js < NJS; ++js) {
        // Counted wait: my js loads done (in-order vmcnt retirement); keep
        // future subtiles in flight across the barrier. Tail peels to 2/0.
        if (js <= NJS - 3)      asm volatile("s_waitcnt vmcnt(4)" ::: "memory");
        else if (js == NJS - 2) asm volatile("s_waitcnt vmcnt(2)" ::: "memory");
        else                    asm volatile("s_waitcnt vmcnt(0)" ::: "memory");
        __builtin_amdgcn_s_barrier();            // raw barrier: no implicit drain
        asm volatile("" ::: "memory");
        __builtin_amdgcn_sched_barrier(0);
        if (js + 3 < NJS) ISSUE_DMA(js + 3, (js + 3) & 3);   // overwrites buf freed at this barrier
        const char* jb8 = (const char*)jbuf[js & 3];
        #pragma unroll
        for (int tile = 0; tile < 2; ++tile) {
            const char* rowp = jb8 + (tile * 16 + lr) * 256;
            short8 ah0 = *(const short8*)(rowp + ((( 0 + lq) ^ lr) << 4));
            short8 ah1 = *(const short8*)(rowp + ((( 4 + lq) ^ lr) << 4));
            short8 al0 = *(const short8*)(rowp + ((( 8 + lq) ^ lr) << 4));
            short8 al1 = *(const short8*)(rowp + (((12 + lq) ^ lr) << 4));
            f32x4 accA = {0.f, 0.f, 0.f, 0.f};
            f32x4 accB = {0.f, 0.f, 0.f, 0.f};
            accA = __builtin_amdgcn_mfma_f32_16x16x32_bf16(ah0, bA0, accA, 0, 0, 0);
            accB = __builtin_amdgcn_mfma_f32_16x16x32_bf16(ah0, bB0, accB, 0, 0, 0);
            accA = __builtin_amdgcn_mfma_f32_16x16x32_bf16(ah1, bA1, accA, 0, 0, 0);
            accB = __builtin_amdgcn_mfma_f32_16x16x32_bf16(ah1, bB1, accB, 0, 0, 0);
            accA = __builtin_amdgcn_mfma_f32_16x16x32_bf16(al0, bA0, accA, 0, 0, 0);
            accB = __builtin_amdgcn_mfma_f32_16x16x32_bf16(al0, bB0, accB, 0, 0, 0);
            accA = __builtin_amdgcn_mfma_f32_16x16x32_bf16(al1, bA1, accA, 0, 0, 0);
            accB = __builtin_amdgcn_mfma_f32_16x16x32_bf16(al1, bB1, accB, 0, 0, 0);
            accA = __builtin_amdgcn_mfma_f32_16x16x32_bf16(ah0, bA4, accA, 0, 0, 0);
            accB = __builtin_amdgcn_mfma_f32_16x16x32_bf16(ah0, bB4, accB, 0, 0, 0);
            accA = __builtin_amdgcn_mfma_f32_16x16x32_bf16(ah1, bA5, accA, 0, 0, 0);
            accB = __builtin_amdgcn_mfma_f32_16x16x32_bf16(ah1, bB5, accB, 0, 0, 0);
            float4 nv = *(const float4*)(nsqs + js * 32 + tile * 16 + lq * 4);
            int idb = ((js * 2 + tile) << 2) | (lq << 8);   // 10-bit id base
            #define INS(K0, K1, K2, K3, sv, idv) {                                  \
                unsigned uu = (__float_as_uint(sv) & 0xFFFFFC00u) | (unsigned)(idv); \
                float kf = __uint_as_float(uu);                                      \
                float n0 = fminf(K0, kf);                                            \
                float n1 = __builtin_amdgcn_fmed3f(K0, K1, kf);                      \
                float n2 = __builtin_amdgcn_fmed3f(K1, K2, kf);                      \
                float n3 = __builtin_amdgcn_fmed3f(K2, K3, kf);                      \
                K0 = n0; K1 = n1; K2 = n2; K3 = n3; }
            {
                float s0 = fmaf(-2.f, accA[0], nv.x + niA); INS(kA0, kA1, kA2, kA3, s0, idb + 0);
                float s1 = fmaf(-2.f, accA[1], nv.y + niA); INS(kA0, kA1, kA2, kA3, s1, idb + 1);
                float s2 = fmaf(-2.f, accA[2], nv.z + niA); INS(kA0, kA1, kA2, kA3, s2, idb + 2);
                float s3 = fmaf(-2.f, accA[3], nv.w + niA); INS(kA0, kA1, kA2, kA3, s3, idb + 3);
            }
            {
                float s0 = fmaf(-2.f, accB[0], nv.x + niB); INS(kB0, kB1, kB2, kB3, s0, idb + 0);
                float s1 = fmaf(-2.f, accB[1], nv.y + niB); INS(kB0, kB1, kB2, kB3, s1, idb + 1);
                float s2 = fmaf(-2.f, accB[2], nv.z + niB); INS(kB0, kB1, kB2, kB3, s2, idb + 2);
                float s3 = fmaf(-2.f, accB[3], nv.w + niB); INS(kB0, kB1, kB2, kB3, s3, idb + 3);
            }
            #undef INS
        }
    }

    // Epilogue: merge 4 lq-stripes per row -> top-4 of 16, decode, write cand.
    __syncthreads();
    float* fbuf = (float*)jbuf;                 // 128 rows x 16 keys = 8 KB
    {
        float* pa = fbuf + (w * 32 + lr) * 16 + lq * 4;
        pa[0] = kA0; pa[1] = kA1; pa[2] = kA2; pa[3] = kA3;
        float* pb = fbuf + (w * 32 + 16 + lr) * 16 + lq * 4;
        pb[0] = kB0; pb[1] = kB1; pb[2] = kB2; pb[3] = kB3;
    }
    __syncthreads();
    if (l < 32) {
        int rloc = w * 32 + l;
        const float* pr = fbuf + rloc * 16;
        float m0 = INF, m1 = INF, m2 = INF, m3 = INF;
        #pragma unroll
        for (int q2 = 0; q2 < 16; ++q2) {
            float kf = pr[q2];
            float n0 = fminf(m0, kf);
            float n1 = __builtin_amdgcn_fmed3f(m0, m1, kf);
            float n2 = __builtin_amdgcn_fmed3f(m1, m2, kf);
            float n3 = __builtin_amdgcn_fmed3f(m2, m3, kf);
            m0 = n0; m1 = n1; m2 = n2; m3 = n3;
        }
        ushortx4 cv;
        #define DEC(mf, slot) { unsigned u = __float_as_uint(mf) & 1023u;            \
            cv[slot] = (ushort)(jBase + (((u >> 2) & 63u) << 4) + ((u >> 8) << 2) + (u & 3)); }
        DEC(m0, 0); DEC(m1, 1); DEC(m2, 2); DEC(m3, 3);
        #undef DEC
        int row = b * T_ + i0 + rloc;
        *(ushortx4*)(cand + (size_t)row * 16 + h * 4) = cv;
    }
}

// ---------------------------------------------------------------------------
// Fused refine + gather + conv v5. Block = (b, 16-i tile), 256 thr, 2048
// blocks = 8 blocks/CU (launch_bounds(256,8) -> VGPR<=64 tier, LDS 12.5 KB).
// XCD-pinned: batch bb on XCD bb%8. The doubled block TLP hides the phase-1
// gather latency chains that 4 blocks/CU could not (R3 post-mortem:
// stall/busy ~3.4 at exactly 4 blocks/CU).
// Phase 1: wave-local query stage; per wave 4 rows x 16 cands, gathers in
//   2-row sub-batches (8 float4 in flight, fits 64-VGPR cap). Score
//   arithmetic, candidate order, lex top-3 scan bitwise-identical to R4.
// Phase 2: gather (192 threads, 4 lanes/row, 64B contiguous).
// Phase 3: conv; thread = (oq, i'), per-(o,i') fmaf chain over mm identical.
// ---------------------------------------------------------------------------
__global__ __launch_bounds__(256, 8) void conv_fused_kernel(const float* __restrict__ ws,
                                                            const float* __restrict__ bias,
                                                            float* __restrict__ out) {
    const float*  xT   = ws + XT_OFF;
    const float*  nsq  = ws + NSQ_OFF;
    const float*  Wt   = ws + WT_OFF;
    const ushort* cand = (const ushort*)(ws + CAND_OFF);

    __shared__ float g_s[192 * 16];            // 12 KB; aliased by refine bufs
    __shared__ int   jsel3[16 * 3];

    // refine scratch aliases (dead before phase 2 writes g_s)
    float* sref = g_s;                          // [16][17] = 272 f
    int*   jref = (int*)(g_s + 272);            // [16][17] = 272 f
    float* q_s  = g_s + 544;                    // [16][68] = 1088 f (tot 1632<3072)

    int bid = blockIdx.x;
    // XCD-pinned bijective decode: XCD = bid%8 owns batches {bid%8, bid%8+8}
    int bb  = (bid & 7) + 8 * (bid >> 10);
    int i0  = ((bid >> 3) & 127) * 16;
    int tid = threadIdx.x;
    int w = tid >> 6, l = tid & 63;
    int bT = bb * T_;

    // --- Phase 1a: stage the 16 query rows into LDS. row = tid>>4 puts wave
    // w's stores exactly on rows w*4..w*4+3 == the rows it refines below ->
    // wave-local, no barrier needed.
    {
        int row = tid >> 4, c4 = tid & 15;
        *(float4*)(q_s + row * 68 + c4 * 4) =
            *(const float4*)(xT + (size_t)(bT + i0 + row) * 64 + c4 * 4);
    }

    // --- Phase 1b: exact refine. lane = (cand cd, chunk c16); wave w owns
    // rows w*4..w*4+3. Gathers in 2-row sub-batches (8 float4 in flight).
    const float INF = __builtin_inff();
    int cd  = l >> 2;          // candidate index 0..15
    int c16 = l & 3;           // 16-channel chunk
    int rbase = i0 + w * 4;
    int jtA[4];
    #pragma unroll
    for (int rr = 0; rr < 4; ++rr)
        jtA[rr] = cand[(size_t)(bT + rbase + rr) * 16 + cd];
    float nsqj[4];
    #pragma unroll
    for (int rr = 0; rr < 4; ++rr)
        nsqj[rr] = nsq[bT + jtA[rr]];

    #pragma unroll
    for (int rp = 0; rp < 2; ++rp) {
        float4 bv0[2], bv1[2], bv2[2], bv3[2];
        #pragma unroll
        for (int r2 = 0; r2 < 2; ++r2) {
            const float4* bp = (const float4*)(xT + (size_t)(bT + jtA[rp * 2 + r2]) * 64 + c16 * 16);
            bv0[r2] = bp[0]; bv1[r2] = bp[1]; bv2[r2] = bp[2]; bv3[r2] = bp[3];
        }
        #pragma unroll
        for (int r2 = 0; r2 < 2; ++r2) {
            int rl = w * 4 + rp * 2 + r2;
            int jt = jtA[rp * 2 + r2];
            const float4* ap = (const float4*)(q_s + rl * 68 + c16 * 16);
            float4 a0 = ap[0], a1 = ap[1], a2 = ap[2], a3 = ap[3];
            float4 b0 = bv0[r2], b1 = bv1[r2], b2 = bv2[r2], b3 = bv3[r2];
            float p0 = fmaf(b0.w, a0.w, fmaf(b0.z, a0.z, fmaf(b0.y, a0.y, b0.x * a0.x)));
            float p1 = fmaf(b1.w, a1.w, fmaf(b1.z, a1.z, fmaf(b1.y, a1.y, b1.x * a1.x)));
            float p2 = fmaf(b2.w, a2.w, fmaf(b2.z, a2.z, fmaf(b2.y, a2.y, b2.x * a2.x)));
            float p3 = fmaf(b3.w, a3.w, fmaf(b3.z, a3.z, fmaf(b3.y, a3.y, b3.x * a3.x)));
            float p = (p0 + p1) + (p2 + p3);       // xor1 + xor2 pairing
            p += __shfl_xor(p, 1, 64);             // xor4 pairing
            p += __shfl_xor(p, 2, 64);             // xor8 pairing
            float s = nsqj[rp * 2 + r2] - 2.f * p;
            if (c16 == 0) { sref[rl * 17 + cd] = s; jref[rl * 17 + cd] = jt; }
        }
    }
    __syncthreads();

    // --- Phase 1c: per-row lex top-3 scan (identical insertion state machine)
    if (tid < 16) {
        const float* sp = sref + tid * 17;
        const int*   jp = jref + tid * 17;
        float D0 = INF, D1 = INF, D2 = INF;
        int   I0 = 0x7FFFFFFF, I1 = 0x7FFFFFFF, I2 = 0x7FFFFFFF;
        #pragma unroll
        for (int t = 0; t < 16; ++t) {
            float s  = sp[t];
            int   jt = jp[t];
            bool lt2 = (s < D2) || (s == D2 && jt < I2);
            bool lt1 = (s < D1) || (s == D1 && jt < I1);
            bool lt0 = (s < D0) || (s == D0 && jt < I0);
            float nD2 = lt1 ? D1 : (lt2 ? s : D2); int nI2 = lt1 ? I1 : (lt2 ? jt : I2);
            float nD1 = lt0 ? D0 : (lt1 ? s : D1); int nI1 = lt0 ? I0 : (lt1 ? jt : I1);
            D2 = nD2; I2 = nI2; D1 = nD1; I1 = nI1;
            D0 = lt0 ? s : D0; I0 = lt0 ? jt : I0;
        }
        jsel3[tid * 3 + 0] = I0; jsel3[tid * 3 + 1] = I1; jsel3[tid * 3 + 2] = I2;
    }
    __syncthreads();

    // --- Phase 2: gather 3 neighbor rows per i' -> g_s[m][i'] (192 threads,
    // 4 threads per (k,row): 64B-contiguous quarters of the 64-channel row)
    if (tid < 192) {
        int k  = tid >> 6;            // 0..2
        int r6 = tid & 63;
        int ip = r6 >> 2;             // 0..15
        int q8 = r6 & 3;              // quarter
        int j = jsel3[ip * 3 + k];
        const float4* src = (const float4*)(xT + (size_t)(bT + j) * 64 + q8 * 16);
        #pragma unroll
        for (int q = 0; q < 4; ++q) {
            float4 v = src[q];
            int mm = k * 64 + q8 * 16 + q * 4;
            g_s[(mm + 0) * 16 + ip] = v.x;
            g_s[(mm + 1) * 16 + ip] = v.y;
            g_s[(mm + 2) * 16 + ip] = v.z;
            g_s[(mm + 3) * 16 + ip] = v.w;
        }
    }
    __syncthreads();

    // --- Phase 3: conv. thread = 4o x 1i; wv float4 (global, L1 broadcast),
    // gv scalar (LDS, 4-lane broadcast). Per-(o,i) accumulation order
    // identical to R6 (mm ascending, same fmaf chain).
    int oq = tid >> 4;        // o = oq*4 .. +3
    int iq = tid & 15;        // i' = iq
    float a0 = 0.f, a1 = 0.f, a2 = 0.f, a3 = 0.f;
    #pragma unroll 4
    for (int mm = 0; mm < 192; ++mm) {
        float4 wv = *(const float4*)(Wt + mm * 64 + oq * 4);
        float  gv = g_s[mm * 16 + iq];
        a0 = fmaf(wv.x, gv, a0);
        a1 = fmaf(wv.y, gv, a1);
        a2 = fmaf(wv.z, gv, a2);
        a3 = fmaf(wv.w, gv, a3);
    }
    int o0 = oq * 4;
    size_t ob = (size_t)(bb * O_ + o0) * T_ + i0 + iq;
    out[ob]          = a0 + bias[o0];
    out[ob + T_]     = a1 + bias[o0 + 1];
    out[ob + 2 * T_] = a2 + bias[o0 + 2];
    out[ob + 3 * T_] = a3 + bias[o0 + 3];
}

// ---------------------------------------------------------------------------
extern "C" void kernel_launch(void* const* d_in, const int* in_sizes, int n_in,
                              void* d_out, int out_size, void* d_ws, size_t ws_size,
                              hipStream_t stream) {
    const float* x    = (const float*)d_in[0];
    const float* W    = (const float*)d_in[1];
    const float* bias = (const float*)d_in[2];
    float* out = (float*)d_out;
    float* ws  = (float*)d_ws;
    // requires ~18.0 MB workspace (<= 21.2 MB proven)

    prep_kernel<<<B_ * (T_ / 64) + 48, 256, 0, stream>>>(x, W, ws);
    knn_mfma_kernel<<<1024, 256, 0, stream>>>(
        (const ushort*)(ws + XS_OFF), ws + NSQ_OFF, (ushort*)(ws + CAND_OFF));
    conv_fused_kernel<<<B_ * 128, 256, 0, stream>>>(ws, bias, out);
}

// Round 8
// 136.266 us; speedup vs baseline: 1.1650x; 1.1650x over previous
//
#include <hip/hip_runtime.h>

// Problem constants (fixed by reference)
#define B_ 16
#define C_ 64
#define T_ 2048
#define O_ 64
#define KNN 3
#define HSPLIT 4
#define JCH (T_ / HSPLIT)     // 512 j per (b,h) chunk
#define NJS (JCH / 32)        // 16 staged 32-row j-subtiles per chunk

typedef short short8   __attribute__((ext_vector_type(8)));   // 8 bf16
typedef float f32x4    __attribute__((ext_vector_type(4)));
typedef unsigned short ushortx4 __attribute__((ext_vector_type(4)));

// Workspace layout (float slots). Total ~18.0 MB (< 21.2 MB proven footprint).
#define XT_OFF 0                              // fp32 xT[b][t][c]          : B*T*64
#define XS_OFF (XT_OFF + B_ * T_ * C_)        // ushort xs[b][t][128] hi|lo
#define NSQ_OFF (XS_OFF + B_ * T_ * C_)       // fp32 nsq[b*T+t]
#define WT_OFF (NSQ_OFF + B_ * T_)            // fp32 Wt[m][o], m=k*64+c   : 192*64
#define CAND_OFF (WT_OFF + 192 * O_)          // ushort cand[B*T][16]

__device__ inline ushort bf16_rne(float f) {
    union { float f; unsigned u; } cv; cv.f = f;
    unsigned u = cv.u;
    u += 0x7FFF + ((u >> 16) & 1);
    return (ushort)(u >> 16);
}
__device__ inline float bf16_val(ushort h) {
    union { unsigned u; float f; } cv; cv.u = ((unsigned)h) << 16; return cv.f;
}

// ---------------------------------------------------------------------------
// Prep v2 (vectorized stores): x (B,C,T) -> xT (B,T,C) fp32, xs bf16 [hi|lo],
// nsq, W (O,C,K) -> Wt[k*64+c][o]. Per-element hi/lo math and the nsq fmaf
// chain are bitwise-identical to the validated R4-R6 prep; only the store
// packing changed (float4 xT, ushort4 xs hi/lo, float4 x loads along T).
// ---------------------------------------------------------------------------
__global__ __launch_bounds__(256) void prep_kernel(const float* __restrict__ x,
                                                   const float* __restrict__ W,
                                                   float* __restrict__ ws) {
    float*  xT  = ws + XT_OFF;
    ushort* xs  = (ushort*)(ws + XS_OFF);
    float*  nsq = ws + NSQ_OFF;
    float*  Wt  = ws + WT_OFF;
    int blk = blockIdx.x;
    int tid = threadIdx.x;
    if (blk < B_ * (T_ / 64)) {
        int b  = blk / (T_ / 64);
        int t0 = (blk % (T_ / 64)) * 64;
        __shared__ float tl[64 * 65];
        #pragma unroll
        for (int r = 0; r < 4; ++r) {
            int c  = r * 16 + (tid >> 4);
            int t4 = (tid & 15) * 4;
            float4 v = *(const float4*)(x + (size_t)(b * C_ + c) * T_ + t0 + t4);
            tl[c * 65 + t4 + 0] = v.x;
            tl[c * 65 + t4 + 1] = v.y;
            tl[c * 65 + t4 + 2] = v.z;
            tl[c * 65 + t4 + 3] = v.w;
        }
        __syncthreads();
        #pragma unroll
        for (int r = 0; r < 4; ++r) {
            int t  = r * 16 + (tid >> 4);
            int c0 = (tid & 15) * 4;
            float v0 = tl[(c0 + 0) * 65 + t];
            float v1 = tl[(c0 + 1) * 65 + t];
            float v2 = tl[(c0 + 2) * 65 + t];
            float v3 = tl[(c0 + 3) * 65 + t];
            size_t rowg = (size_t)(b * T_ + t0 + t);
            float4 xv; xv.x = v0; xv.y = v1; xv.z = v2; xv.w = v3;
            *(float4*)(xT + rowg * 64 + c0) = xv;
            ushort h0 = bf16_rne(v0), h1 = bf16_rne(v1);
            ushort h2 = bf16_rne(v2), h3 = bf16_rne(v3);
            ushortx4 hv; hv[0] = h0; hv[1] = h1; hv[2] = h2; hv[3] = h3;
            ushortx4 lv;
            lv[0] = bf16_rne(v0 - bf16_val(h0));
            lv[1] = bf16_rne(v1 - bf16_val(h1));
            lv[2] = bf16_rne(v2 - bf16_val(h2));
            lv[3] = bf16_rne(v3 - bf16_val(h3));
            *(ushortx4*)(xs + rowg * 128 + c0)      = hv;
            *(ushortx4*)(xs + rowg * 128 + 64 + c0) = lv;
        }
        if (tid < 64) {
            float s = 0.f;
            #pragma unroll
            for (int c = 0; c < 64; ++c) { float v = tl[c * 65 + tid]; s = fmaf(v, v, s); }
            nsq[b * T_ + t0 + tid] = s;
        }
    } else {
        int e = (blk - B_ * (T_ / 64)) * 256 + tid;
        if (e < O_ * C_ * KNN) {
            int o = e / (C_ * KNN);
            int c = (e / KNN) % C_;
            int k = e % KNN;
            Wt[(k * 64 + c) * O_ + o] = W[e];
        }
    }
}

// ---------------------------------------------------------------------------
// KNN screen v4 (MFMA) + XCD pinning: batch b runs only on XCD b%8 (2
// batches/XCD) so xs/nsq stay L2-resident per XCD. Counted-vmcnt 3-deep DMA
// pipeline (T3/T4) unchanged.
// ---------------------------------------------------------------------------
__global__ __launch_bounds__(256, 4) void knn_mfma_kernel(const ushort* __restrict__ xs,
                                                          const float* __restrict__ nsq,
                                                          ushort* __restrict__ cand) {
    __shared__ __align__(16) ushort jbuf[4][32 * 128];   // 4 x 8 KB, XOR-swizzled
    __shared__ float nsqs[JCH];                          // 2 KB

    int bid = blockIdx.x;
    // XCD-pinned bijective decode: XCD = bid%8 owns batches {bid%8, bid%8+8}
    int b   = (bid & 7) + 8 * (bid >> 9);
    int h   = (bid >> 3) & 3;
    int m   = (bid >> 5) & 15;
    int i0  = m * 128;
    int tid = threadIdx.x;
    int w   = tid >> 6, l = tid & 63, lr = l & 15, lq = l >> 4;
    const ushort* xsb = xs + (size_t)b * T_ * 128;
    int jBase = h * JCH;

    if (tid < JCH / 4)
        ((float4*)nsqs)[tid] = ((const float4*)(nsq + b * T_ + jBase))[tid];

    // B-operand frags for 2 i-sets: rows i0+w*32+lr (A) and +16 (B)
    short8 bA0, bA1, bA4, bA5, bB0, bB1, bB4, bB5;
    {
        const ushort* ia = xsb + (size_t)(i0 + w * 32 + lr) * 128 + lq * 8;
        bA0 = *(const short8*)(ia + 0);  bA1 = *(const short8*)(ia + 32);
        bA4 = *(const short8*)(ia + 64); bA5 = *(const short8*)(ia + 96);
        const ushort* ib2 = ia + 16 * 128;
        bB0 = *(const short8*)(ib2 + 0);  bB1 = *(const short8*)(ib2 + 32);
        bB4 = *(const short8*)(ib2 + 64); bB5 = *(const short8*)(ib2 + 96);
    }
    float niA = nsq[b * T_ + i0 + w * 32 + lr] + 4.0f;
    float niB = nsq[b * T_ + i0 + w * 32 + 16 + lr] + 4.0f;

    const float INF = __builtin_inff();
    float kA0 = INF, kA1 = INF, kA2 = INF, kA3 = INF;
    float kB0 = INF, kB1 = INF, kB2 = INF, kB3 = INF;

    int cSw = lr ^ (w * 4 + lq);                 // swizzled source chunk
    #define ISSUE_DMA(jsv, bufv) {                                               \
        _Pragma("unroll")                                                        \
        for (int p = 0; p < 2; ++p) {                                            \
            int rloc = p * 16 + w * 4 + lq;                                      \
            const ushort* gp = xsb + (size_t)(jBase + (jsv) * 32 + rloc) * 128 + cSw * 8; \
            __builtin_amdgcn_global_load_lds(                                    \
                (const __attribute__((address_space(1))) void*)gp,               \
                (__attribute__((address_space(3))) void*)(jbuf[bufv] + (p * 16 + w * 4) * 128), \
                16, 0, 0);                                                       \
        } }

    // Drain the nsqs ds_write so it is visible to all waves after barrier 0.
    asm volatile("s_waitcnt lgkmcnt(0)" ::: "memory");

    // Prologue: 3 subtiles in flight.
    ISSUE_DMA(0, 0);
    ISSUE_DMA(1, 1);
    ISSUE_DMA(2, 2);

    #pragma unroll 1
    for (int js = 0; js < NJS; ++js) {
        // Counted wait: my js loads done (in-order vmcnt retirement); keep
        // future subtiles in flight across the barrier. Tail peels to 2/0.
        if (js <= NJS - 3)      asm volatile("s_waitcnt vmcnt(4)" ::: "memory");
        else if (js == NJS - 2) asm volatile("s_waitcnt vmcnt(2)" ::: "memory");
        else                    asm volatile("s_waitcnt vmcnt(0)" ::: "memory");
        __builtin_amdgcn_s_barrier();            // raw barrier: no implicit drain
        asm volatile("" ::: "memory");
        __builtin_amdgcn_sched_barrier(0);
        if (js + 3 < NJS) ISSUE_DMA(js + 3, (js + 3) & 3);   // overwrites buf freed at this barrier
        const char* jb8 = (const char*)jbuf[js & 3];
        #pragma unroll
        for (int tile = 0; tile < 2; ++tile) {
            const char* rowp = jb8 + (tile * 16 + lr) * 256;
            short8 ah0 = *(const short8*)(rowp + ((( 0 + lq) ^ lr) << 4));
            short8 ah1 = *(const short8*)(rowp + ((( 4 + lq) ^ lr) << 4));
            short8 al0 = *(const short8*)(rowp + ((( 8 + lq) ^ lr) << 4));
            short8 al1 = *(const short8*)(rowp + (((12 + lq) ^ lr) << 4));
            f32x4 accA = {0.f, 0.f, 0.f, 0.f};
            f32x4 accB = {0.f, 0.f, 0.f, 0.f};
            accA = __builtin_amdgcn_mfma_f32_16x16x32_bf16(ah0, bA0, accA, 0, 0, 0);
            accB = __builtin_amdgcn_mfma_f32_16x16x32_bf16(ah0, bB0, accB, 0, 0, 0);
            accA = __builtin_amdgcn_mfma_f32_16x16x32_bf16(ah1, bA1, accA, 0, 0, 0);
            accB = __builtin_amdgcn_mfma_f32_16x16x32_bf16(ah1, bB1, accB, 0, 0, 0);
            accA = __builtin_amdgcn_mfma_f32_16x16x32_bf16(al0, bA0, accA, 0, 0, 0);
            accB = __builtin_amdgcn_mfma_f32_16x16x32_bf16(al0, bB0, accB, 0, 0, 0);
            accA = __builtin_amdgcn_mfma_f32_16x16x32_bf16(al1, bA1, accA, 0, 0, 0);
            accB = __builtin_amdgcn_mfma_f32_16x16x32_bf16(al1, bB1, accB, 0, 0, 0);
            accA = __builtin_amdgcn_mfma_f32_16x16x32_bf16(ah0, bA4, accA, 0, 0, 0);
            accB = __builtin_amdgcn_mfma_f32_16x16x32_bf16(ah0, bB4, accB, 0, 0, 0);
            accA = __builtin_amdgcn_mfma_f32_16x16x32_bf16(ah1, bA5, accA, 0, 0, 0);
            accB = __builtin_amdgcn_mfma_f32_16x16x32_bf16(ah1, bB5, accB, 0, 0, 0);
            float4 nv = *(const float4*)(nsqs + js * 32 + tile * 16 + lq * 4);
            int idb = ((js * 2 + tile) << 2) | (lq << 8);   // 10-bit id base
            #define INS(K0, K1, K2, K3, sv, idv) {                                  \
                unsigned uu = (__float_as_uint(sv) & 0xFFFFFC00u) | (unsigned)(idv); \
                float kf = __uint_as_float(uu);                                      \
                float n0 = fminf(K0, kf);                                            \
                float n1 = __builtin_amdgcn_fmed3f(K0, K1, kf);                      \
                float n2 = __builtin_amdgcn_fmed3f(K1, K2, kf);                      \
                float n3 = __builtin_amdgcn_fmed3f(K2, K3, kf);                      \
                K0 = n0; K1 = n1; K2 = n2; K3 = n3; }
            {
                float s0 = fmaf(-2.f, accA[0], nv.x + niA); INS(kA0, kA1, kA2, kA3, s0, idb + 0);
                float s1 = fmaf(-2.f, accA[1], nv.y + niA); INS(kA0, kA1, kA2, kA3, s1, idb + 1);
                float s2 = fmaf(-2.f, accA[2], nv.z + niA); INS(kA0, kA1, kA2, kA3, s2, idb + 2);
                float s3 = fmaf(-2.f, accA[3], nv.w + niA); INS(kA0, kA1, kA2, kA3, s3, idb + 3);
            }
            {
                float s0 = fmaf(-2.f, accB[0], nv.x + niB); INS(kB0, kB1, kB2, kB3, s0, idb + 0);
                float s1 = fmaf(-2.f, accB[1], nv.y + niB); INS(kB0, kB1, kB2, kB3, s1, idb + 1);
                float s2 = fmaf(-2.f, accB[2], nv.z + niB); INS(kB0, kB1, kB2, kB3, s2, idb + 2);
                float s3 = fmaf(-2.f, accB[3], nv.w + niB); INS(kB0, kB1, kB2, kB3, s3, idb + 3);
            }
            #undef INS
        }
    }

    // Epilogue: merge 4 lq-stripes per row -> top-4 of 16, decode, write cand.
    __syncthreads();
    float* fbuf = (float*)jbuf;                 // 128 rows x 16 keys = 8 KB
    {
        float* pa = fbuf + (w * 32 + lr) * 16 + lq * 4;
        pa[0] = kA0; pa[1] = kA1; pa[2] = kA2; pa[3] = kA3;
        float* pb = fbuf + (w * 32 + 16 + lr) * 16 + lq * 4;
        pb[0] = kB0; pb[1] = kB1; pb[2] = kB2; pb[3] = kB3;
    }
    __syncthreads();
    if (l < 32) {
        int rloc = w * 32 + l;
        const float* pr = fbuf + rloc * 16;
        float m0 = INF, m1 = INF, m2 = INF, m3 = INF;
        #pragma unroll
        for (int q2 = 0; q2 < 16; ++q2) {
            float kf = pr[q2];
            float n0 = fminf(m0, kf);
            float n1 = __builtin_amdgcn_fmed3f(m0, m1, kf);
            float n2 = __builtin_amdgcn_fmed3f(m1, m2, kf);
            float n3 = __builtin_amdgcn_fmed3f(m2, m3, kf);
            m0 = n0; m1 = n1; m2 = n2; m3 = n3;
        }
        ushortx4 cv;
        #define DEC(mf, slot) { unsigned u = __float_as_uint(mf) & 1023u;            \
            cv[slot] = (ushort)(jBase + (((u >> 2) & 63u) << 4) + ((u >> 8) << 2) + (u & 3)); }
        DEC(m0, 0); DEC(m1, 1); DEC(m2, 2); DEC(m3, 3);
        #undef DEC
        int row = b * T_ + i0 + rloc;
        *(ushortx4*)(cand + (size_t)row * 16 + h * 4) = cv;
    }
}

// ---------------------------------------------------------------------------
// Fused refine + gather + conv (R3 version, measured 40.6 us). Block =
// (b, 32-i tile), 256 thr, 1024 blocks, XCD-pinned: batch bb on XCD bb%8.
// Phase 1 (MLP refine): query rows staged in LDS (wave-local, no barrier);
//   per wave all 8 cand ids + nsq preloaded; candidate gathers batched 4 rows
//   at a time into named float4[4][4] registers (64 VGPRs in flight).
//   Summation pairing and lex top-3 scan bitwise-identical.
// Phase 2: gather (192 threads). Phase 3: conv, fmaf chain identical to R6.
// NOTE (R4 lesson): do NOT raise blocks/CU here — launch_bounds(256,8)
// squeezes VGPR to 32 and re-serializes the gathers (40.6 -> 65.8 us).
// ---------------------------------------------------------------------------
__global__ __launch_bounds__(256, 4) void conv_fused_kernel(const float* __restrict__ ws,
                                                            const float* __restrict__ bias,
                                                            float* __restrict__ out) {
    const float*  xT   = ws + XT_OFF;
    const float*  nsq  = ws + NSQ_OFF;
    const float*  Wt   = ws + WT_OFF;
    const ushort* cand = (const ushort*)(ws + CAND_OFF);

    __shared__ float g_s[192 * 32];            // 24 KB; aliased by refine bufs
    __shared__ int   jsel3[32 * 3];

    // refine scratch aliases (dead before phase 2 writes g_s)
    float* sref = g_s;                          // [32][17] padded stride  (544 f)
    int*   jref = (int*)(g_s + 32 * 17);        // [32][17]                (544 f)
    float* q_s  = g_s + 1152;                   // [32][68] query rows     (2176 f)

    int bid = blockIdx.x;
    // XCD-pinned bijective decode: XCD = bid%8 owns batches {bid%8, bid%8+8}
    int bb  = (bid & 7) + 8 * (bid >> 9);
    int i0  = ((bid >> 3) & 63) * 32;
    int tid = threadIdx.x;
    int w = tid >> 6, l = tid & 63;
    int bT = bb * T_;

    // --- Phase 1a: stage the 32 query rows into LDS (coalesced; each wave
    // stages exactly the 8 rows it will refine -> wave-local, no barrier)
    {
        int row = tid >> 3;            // 0..31
        int c8  = tid & 7;             // 8-float chunk
        const float4* src = (const float4*)(xT + (size_t)(bT + i0 + row) * 64 + c8 * 8);
        float4 v0 = src[0], v1 = src[1];
        *(float4*)(q_s + row * 68 + c8 * 8)     = v0;
        *(float4*)(q_s + row * 68 + c8 * 8 + 4) = v1;
    }

    // --- Phase 1b: exact refine. lane = (cand cd, chunk c16); wave w owns
    // rows w*8..w*8+7. All cand ids + nsq preloaded; gathers batched 4 rows
    // deep (16 float4 in flight).
    const float INF = __builtin_inff();
    int cd  = l >> 2;          // candidate index 0..15
    int c16 = l & 3;           // 16-channel chunk
    int rbase = i0 + w * 8;
    int jtA[8];
    #pragma unroll
    for (int rr = 0; rr < 8; ++rr)
        jtA[rr] = cand[(size_t)(bT + rbase + rr) * 16 + cd];
    float nsqj[8];
    #pragma unroll
    for (int rr = 0; rr < 8; ++rr)
        nsqj[rr] = nsq[bT + jtA[rr]];

    #pragma unroll
    for (int rp = 0; rp < 2; ++rp) {
        float4 bv0[4], bv1[4], bv2[4], bv3[4];
        #pragma unroll
        for (int r4 = 0; r4 < 4; ++r4) {
            const float4* bp = (const float4*)(xT + (size_t)(bT + jtA[rp * 4 + r4]) * 64 + c16 * 16);
            bv0[r4] = bp[0]; bv1[r4] = bp[1]; bv2[r4] = bp[2]; bv3[r4] = bp[3];
        }
        #pragma unroll
        for (int r4 = 0; r4 < 4; ++r4) {
            int rl = w * 8 + rp * 4 + r4;
            int jt = jtA[rp * 4 + r4];
            const float4* ap = (const float4*)(q_s + rl * 68 + c16 * 16);
            float4 a0 = ap[0], a1 = ap[1], a2 = ap[2], a3 = ap[3];
            float4 b0 = bv0[r4], b1 = bv1[r4], b2 = bv2[r4], b3 = bv3[r4];
            float p0 = fmaf(b0.w, a0.w, fmaf(b0.z, a0.z, fmaf(b0.y, a0.y, b0.x * a0.x)));
            float p1 = fmaf(b1.w, a1.w, fmaf(b1.z, a1.z, fmaf(b1.y, a1.y, b1.x * a1.x)));
            float p2 = fmaf(b2.w, a2.w, fmaf(b2.z, a2.z, fmaf(b2.y, a2.y, b2.x * a2.x)));
            float p3 = fmaf(b3.w, a3.w, fmaf(b3.z, a3.z, fmaf(b3.y, a3.y, b3.x * a3.x)));
            float p = (p0 + p1) + (p2 + p3);       // xor1 + xor2 pairing
            p += __shfl_xor(p, 1, 64);             // xor4 pairing
            p += __shfl_xor(p, 2, 64);             // xor8 pairing
            float s = nsqj[rp * 4 + r4] - 2.f * p;
            if (c16 == 0) { sref[rl * 17 + cd] = s; jref[rl * 17 + cd] = jt; }
        }
    }
    __syncthreads();

    // --- Phase 1c: per-row lex top-3 scan (identical insertion state machine)
    if (tid < 32) {
        const float* sp = sref + tid * 17;
        const int*   jp = jref + tid * 17;
        float D0 = INF, D1 = INF, D2 = INF;
        int   I0 = 0x7FFFFFFF, I1 = 0x7FFFFFFF, I2 = 0x7FFFFFFF;
        #pragma unroll
        for (int t = 0; t < 16; ++t) {
            float s  = sp[t];
            int   jt = jp[t];
            bool lt2 = (s < D2) || (s == D2 && jt < I2);
            bool lt1 = (s < D1) || (s == D1 && jt < I1);
            bool lt0 = (s < D0) || (s == D0 && jt < I0);
            float nD2 = lt1 ? D1 : (lt2 ? s : D2); int nI2 = lt1 ? I1 : (lt2 ? jt : I2);
            float nD1 = lt0 ? D0 : (lt1 ? s : D1); int nI1 = lt0 ? I0 : (lt1 ? jt : I1);
            D2 = nD2; I2 = nI2; D1 = nD1; I1 = nI1;
            D0 = lt0 ? s : D0; I0 = lt0 ? jt : I0;
        }
        jsel3[tid * 3 + 0] = I0; jsel3[tid * 3 + 1] = I1; jsel3[tid * 3 + 2] = I2;
    }
    __syncthreads();

    // --- Phase 2: gather 3 neighbor rows per i' -> g_s[m][i'] (192 threads,
    // 2 threads per (k,row): halves of the 64-channel row)
    if (tid < 192) {
        int k    = tid >> 6;          // 0..2
        int r6   = tid & 63;
        int ip   = r6 >> 1;           // 0..31
        int half = r6 & 1;            // 0..1
        int j = jsel3[ip * 3 + k];
        const float4* src = (const float4*)(xT + (size_t)(bT + j) * 64 + half * 32);
        #pragma unroll
        for (int q = 0; q < 8; ++q) {
            float4 v = src[q];
            int mm = k * 64 + (half * 8 + q) * 4;
            g_s[(mm + 0) * 32 + ip] = v.x;
            g_s[(mm + 1) * 32 + ip] = v.y;
            g_s[(mm + 2) * 32 + ip] = v.z;
            g_s[(mm + 3) * 32 + ip] = v.w;
        }
    }
    __syncthreads();

    // --- Phase 3: conv. thread = 4o x 2i; wv float4 (global, L1 broadcast),
    // gv float2 (LDS). Per-(o,i) accumulation order identical to R6.
    int oq = tid >> 4;        // o = oq*4 .. +3
    int iq = tid & 15;        // i' = iq*2, +1
    float a0x = 0.f, a0y = 0.f, a1x = 0.f, a1y = 0.f;
    float a2x = 0.f, a2y = 0.f, a3x = 0.f, a3y = 0.f;
    #pragma unroll 4
    for (int mm = 0; mm < 192; ++mm) {
        float4 wv = *(const float4*)(Wt + mm * 64 + oq * 4);
        float2 gv = *(const float2*)(g_s + mm * 32 + iq * 2);
        a0x = fmaf(wv.x, gv.x, a0x); a0y = fmaf(wv.x, gv.y, a0y);
        a1x = fmaf(wv.y, gv.x, a1x); a1y = fmaf(wv.y, gv.y, a1y);
        a2x = fmaf(wv.z, gv.x, a2x); a2y = fmaf(wv.z, gv.y, a2y);
        a3x = fmaf(wv.w, gv.x, a3x); a3y = fmaf(wv.w, gv.y, a3y);
    }
    int o0 = oq * 4;
    float b0 = bias[o0], b1 = bias[o0 + 1], b2 = bias[o0 + 2], b3 = bias[o0 + 3];
    float2 r0; r0.x = a0x + b0; r0.y = a0y + b0;
    float2 r1; r1.x = a1x + b1; r1.y = a1y + b1;
    float2 r2; r2.x = a2x + b2; r2.y = a2y + b2;
    float2 r3; r3.x = a3x + b3; r3.y = a3y + b3;
    size_t ob = (size_t)(bb * O_ + o0) * T_ + i0 + iq * 2;
    *(float2*)(out + ob)          = r0;
    *(float2*)(out + ob + T_)     = r1;
    *(float2*)(out + ob + 2 * T_) = r2;
    *(float2*)(out + ob + 3 * T_) = r3;
}

// ---------------------------------------------------------------------------
extern "C" void kernel_launch(void* const* d_in, const int* in_sizes, int n_in,
                              void* d_out, int out_size, void* d_ws, size_t ws_size,
                              hipStream_t stream) {
    const float* x    = (const float*)d_in[0];
    const float* W    = (const float*)d_in[1];
    const float* bias = (const float*)d_in[2];
    float* out = (float*)d_out;
    float* ws  = (float*)d_ws;
    // requires ~18.0 MB workspace (<= 21.2 MB proven)

    prep_kernel<<<B_ * (T_ / 64) + 48, 256, 0, stream>>>(x, W, ws);
    knn_mfma_kernel<<<1024, 256, 0, stream>>>(
        (const ushort*)(ws + XS_OFF), ws + NSQ_OFF, (ushort*)(ws + CAND_OFF));
    conv_fused_kernel<<<B_ * 64, 256, 0, stream>>>(ws, bias, out);
}